// Round 10
// baseline (577.075 us; speedup 1.0000x reference)
//
#include <hip/hip_runtime.h>
#include <stdint.h>

// out = (softmax((x Wq^T + bq)(x Wk^T + bk)^T / sqrt(128)) (x Wv^T + bv)) Wo^T + bo + x
// N=8192, D=1024, bf16 MFMA. S-GEMM: pair-phase (T3+T4+T5) 256^2 with fused exp+rowsum
// (softmax kernel eliminated; PV divides by rowsum). Other GEMMs: verified 2-phase pipeline.

#define NTOK 8192
#define DMOD 1024
static constexpr float INV_SCALE = 0.08838834764831845f; // 1/sqrt(128)

typedef __attribute__((ext_vector_type(8))) short short8;
typedef __attribute__((ext_vector_type(4))) float f32x4;
typedef __attribute__((ext_vector_type(8))) unsigned short u16x8;
typedef __attribute__((ext_vector_type(4))) unsigned short u16x4;

__device__ __forceinline__ unsigned short f2bf(float f) {
  union { float f; uint32_t u; } x{f};
  uint32_t r = x.u + 0x7fffu + ((x.u >> 16) & 1u);
  return (unsigned short)(r >> 16);
}
__device__ __forceinline__ void async16(void* lds, const void* g) {
  __builtin_amdgcn_global_load_lds((const __attribute__((address_space(1))) void*)g,
                                   (__attribute__((address_space(3))) void*)lds, 16, 0, 0);
}
__device__ __forceinline__ f32x4 mfma16(short8 a, short8 b, f32x4 c) {
  return __builtin_amdgcn_mfma_f32_16x16x32_bf16(a, b, c, 0, 0, 0);
}

// ---------------- cast f32 -> bf16 ----------------
__global__ __launch_bounds__(256) void cast_f32_bf16(const float* __restrict__ in,
                                                     unsigned short* __restrict__ out, int n4) {
  int i = blockIdx.x * 256 + threadIdx.x;
  int stride = gridDim.x * 256;
  for (; i < n4; i += stride) {
    float4 v = ((const float4*)in)[i];
    u16x4 o;
    o[0] = f2bf(v.x); o[1] = f2bf(v.y); o[2] = f2bf(v.z); o[3] = f2bf(v.w);
    ((u16x4*)out)[i] = o;
  }
}

__global__ __launch_bounds__(256) void zerof(float* __restrict__ p, int n) {
  int i = blockIdx.x * 256 + threadIdx.x;
  if (i < n) p[i] = 0.f;
}

// ======== pair-phase S-GEMM: P' = exp(Q K^T - 3), rowsum += partials ========
// 256x256, BK=32 tile-pairs (64-K per iteration), 8 waves (2Mg x 4Ng).
// INTERLEAVED frag mapping: frag m -> tile rows (m*2+g)*16, frag n -> cols (n*4+h)*16,
// so quadrant (mh,nh) == LDS half globally. 4 phases/iter, 16 MFMA each.
// Stage ledger (pair p2v=T+2 fills its buffers; p4v=T+4 into the computing buffers):
//   p0: A1(p2v),A1(p2v+1),B1(p2v),B1(p2v+1)   [slots freed at prev iter p3]
//   p2: A0(p4v),A0(p4v+1)                     [A0 last read at p1]
//   p3: B0(p4v),B0(p4v+1)                     [B0 last read at p2]
// wait at p3: vmcnt(4) retires pair (T+2,T+3) fully; leaves A0,B0(T+4).
__global__ __launch_bounds__(512, 2) void gemm_s_exp(
    const unsigned short* __restrict__ A, const unsigned short* __restrict__ B,
    unsigned short* __restrict__ P, float* __restrict__ rowsum,
    int M, int N, int K)
{
  constexpr int BM = 256;
  constexpr int M_REP = 8, N_REP = 4, M2 = 4, N2 = 2;
  constexpr int ABYTES = BM * 64, BUFB = 2 * ABYTES;   // 32 KB / buffer
  constexpr int LOADS = 4;   // li: 0=A-half0, 1=A-half1, 2=B-half0, 3=B-half1

  __shared__ alignas(16) char lds[4 * BUFB];           // 128 KiB

  const int t = threadIdx.x;
  const int l = t & 63, w = t >> 6;
  const int g = w >> 2;   // M group (0..1)
  const int h = w & 3;    // N group (0..3)

  // bijective XCD swizzle (m204)
  const int nwg = gridDim.x * gridDim.y;
  const int flat = blockIdx.y * gridDim.x + blockIdx.x;
  const int q8 = nwg >> 3, r8 = nwg & 7;
  const int xcd = flat & 7, pos = flat >> 3;
  const int swz = (xcd < r8 ? xcd * (q8 + 1) : r8 * (q8 + 1) + (xcd - r8) * q8) + pos;
  const int row0 = (swz / gridDim.x) * BM;
  const int col0 = (swz % gridDim.x) * BM;

  // staging addresses (r6-verified): source col pre-swizzled, LDS dest linear
  const unsigned short* gsrc[LOADS];
  int ldst[LOADS];
#pragma unroll
  for (int li = 0; li < LOADS; ++li) {
    const int byte0 = li * 512 * 16 + t * 16;
    int r; const unsigned short* base;
    if (byte0 < ABYTES) { r = byte0 >> 6; base = A + (size_t)(row0 + r) * K; }
    else { r = (byte0 - ABYTES) >> 6; base = B + (size_t)(col0 + r) * K; }
    const int slot = (byte0 >> 4) & 3;
    gsrc[li] = base + (slot ^ ((r >> 1) & 3)) * 8;
    ldst[li] = byte0;
  }

  // fragment offsets (interleaved mapping)
  int offA[M_REP], offB[N_REP];
#pragma unroll
  for (int m = 0; m < M_REP; ++m) {
    int r = (m * 2 + g) * 16 + (l & 15);
    offA[m] = r * 64 + (((l >> 4) ^ ((r >> 1) & 3)) * 16);
  }
#pragma unroll
  for (int n = 0; n < N_REP; ++n) {
    int r = (n * 4 + h) * 16 + (l & 15);
    offB[n] = ABYTES + r * 64 + (((l >> 4) ^ ((r >> 1) & 3)) * 16);
  }

  f32x4 acc[M_REP][N_REP] = {};
  const int KT = K / 32;
  const int NP = KT / 2;

  // prologue: tiles 0,1 full; A0,B0 of tiles 2,3  (12 asyncs) -> vmcnt(4)
#pragma unroll
  for (int j = 0; j < 2; ++j) {
    char* bb = lds + j * BUFB;
#pragma unroll
    for (int li = 0; li < LOADS; ++li) async16(bb + ldst[li], gsrc[li] + j * 32);
  }
  async16(lds + 2 * BUFB + ldst[0], gsrc[0] + 2 * 32);
  async16(lds + 3 * BUFB + ldst[0], gsrc[0] + 3 * 32);
  async16(lds + 2 * BUFB + ldst[2], gsrc[2] + 2 * 32);
  async16(lds + 3 * BUFB + ldst[2], gsrc[2] + 3 * 32);
  asm volatile("s_waitcnt vmcnt(4)" ::: "memory");
  __builtin_amdgcn_s_barrier();

  for (int I = 0; I < NP; ++I) {
    const int T = 2 * I;
    const char* rb0 = lds + (T & 3) * BUFB;
    const char* rb1 = lds + ((T + 1) & 3) * BUFB;
    const int p2v = T + 2, p4v = T + 4;
    char* s2a = lds + (p2v & 3) * BUFB;
    char* s2b = lds + ((p2v + 1) & 3) * BUFB;
    char* s4a = lds + (p4v & 3) * BUFB;
    char* s4b = lds + ((p4v + 1) & 3) * BUFB;
#pragma unroll
    for (int p = 0; p < 4; ++p) {
      const int mh = (p >> 1) * M2, nh = (p & 1) * N2;
      short8 fa0[M2], fa1[M2], fb0[N2], fb1[N2];
#pragma unroll
      for (int m = 0; m < M2; ++m) {
        fa0[m] = *(const short8*)(rb0 + offA[mh + m]);
        fa1[m] = *(const short8*)(rb1 + offA[mh + m]);
      }
#pragma unroll
      for (int n = 0; n < N2; ++n) {
        fb0[n] = *(const short8*)(rb0 + offB[nh + n]);
        fb1[n] = *(const short8*)(rb1 + offB[nh + n]);
      }
      if (p == 0 && p2v < KT) {
        async16(s2a + ldst[1], gsrc[1] + (size_t)p2v * 32);
        async16(s2b + ldst[1], gsrc[1] + (size_t)(p2v + 1) * 32);
        async16(s2a + ldst[3], gsrc[3] + (size_t)p2v * 32);
        async16(s2b + ldst[3], gsrc[3] + (size_t)(p2v + 1) * 32);
      } else if (p == 2 && p4v < KT) {
        async16(s4a + ldst[0], gsrc[0] + (size_t)p4v * 32);
        async16(s4b + ldst[0], gsrc[0] + (size_t)(p4v + 1) * 32);
      } else if (p == 3 && p4v < KT) {
        async16(s4a + ldst[2], gsrc[2] + (size_t)p4v * 32);
        async16(s4b + ldst[2], gsrc[2] + (size_t)(p4v + 1) * 32);
      }
      __builtin_amdgcn_s_barrier();
      __builtin_amdgcn_s_setprio(1);
#pragma unroll
      for (int m = 0; m < M2; ++m)
#pragma unroll
        for (int n = 0; n < N2; ++n) {
          acc[mh + m][nh + n] = mfma16(fa0[m], fb0[n], acc[mh + m][nh + n]);
          acc[mh + m][nh + n] = mfma16(fa1[m], fb1[n], acc[mh + m][nh + n]);
        }
      __builtin_amdgcn_s_setprio(0);
      if (p == 3) {
        if (p4v < KT) { asm volatile("s_waitcnt vmcnt(4)" ::: "memory"); }
        else { asm volatile("s_waitcnt vmcnt(0)" ::: "memory"); }
      }
      __builtin_amdgcn_s_barrier();
    }
  }

  // epilogue: exp(s-3) (const bias cancels in normalization), rowsum atomics, bf16 write
#pragma unroll
  for (int m = 0; m < M_REP; ++m) {
#pragma unroll
    for (int j = 0; j < 4; ++j) {
      const int r = row0 + (m * 2 + g) * 16 + ((l >> 4) << 2) + j;
      float ev[N_REP];
      float part = 0.f;
#pragma unroll
      for (int n = 0; n < N_REP; ++n) { ev[n] = __expf(acc[m][n][j] - 3.0f); part += ev[n]; }
#pragma unroll
      for (int o = 8; o; o >>= 1) part += __shfl_xor(part, o);
      if ((l & 15) == 0) atomicAdd(&rowsum[r], part);
#pragma unroll
      for (int n = 0; n < N_REP; ++n) {
        const int c = col0 + (n * 4 + h) * 16 + (l & 15);
        P[(size_t)r * N + c] = f2bf(ev[n]);
      }
    }
  }
}

// ======== 2-phase pipelined GEMM (round-6 verified) ========
template<int BM, int BN, int WM, int WN, bool BIAS, bool TRANS, bool F32OUT, bool RES, bool DIVROW>
__global__ __launch_bounds__(WM*WN*64, 2) void gemm_pipe(
    const unsigned short* __restrict__ A, const unsigned short* __restrict__ B,
    unsigned short* __restrict__ O16, float* __restrict__ O32,
    const float* __restrict__ bias, const float* __restrict__ resid,
    const float* __restrict__ rowsum,
    int M, int N, int K, float scale)
{
  constexpr int THREADS = WM * WN * 64;
  constexpr int M_REP = BM / (WM * 16);
  constexpr int N_REP = BN / (WN * 16);
  constexpr int ABYTES = BM * 64;
  constexpr int BBYTES = BN * 64;
  constexpr int BUFB = ABYTES + BBYTES;
  constexpr int RPR = THREADS / 4;
  static_assert(BM == BN, "square tiles only");
  static_assert(BM * 64 == RPR * 64 * 2, "2 staging rounds per operand");

  __shared__ alignas(16) char lds[4 * BUFB];

  const int t = threadIdx.x;
  const int l = t & 63, w = t >> 6;
  const int wrow = (w / WN) * (M_REP * 16);
  const int wcol = (w % WN) * (N_REP * 16);

  const int nwg = gridDim.x * gridDim.y;
  const int flat = blockIdx.y * gridDim.x + blockIdx.x;
  const int q8 = nwg >> 3, r8 = nwg & 7;
  const int xcd = flat & 7, pos = flat >> 3;
  const int swz = (xcd < r8 ? xcd * (q8 + 1) : r8 * (q8 + 1) + (xcd - r8) * q8) + pos;
  const int row0 = (swz / gridDim.x) * BM;
  const int col0 = (swz % gridDim.x) * BN;

  const int sr0 = t >> 2, sr1 = (t >> 2) + RPR;
  const int c0 = ((t & 3) ^ ((sr0 >> 1) & 3)) * 8;
  const int c1 = ((t & 3) ^ ((sr1 >> 1) & 3)) * 8;
  const unsigned short* gsrc[4];
  int ldst[4];
  gsrc[0] = A + (size_t)(row0 + sr0) * K + c0;  ldst[0] = t * 16;
  gsrc[1] = A + (size_t)(row0 + sr1) * K + c1;  ldst[1] = t * 16 + RPR * 64;
  gsrc[2] = B + (size_t)(col0 + sr0) * K + c0;  ldst[2] = ABYTES + t * 16;
  gsrc[3] = B + (size_t)(col0 + sr1) * K + c1;  ldst[3] = ABYTES + t * 16 + RPR * 64;

  int offA[M_REP], offB[N_REP];
#pragma unroll
  for (int m = 0; m < M_REP; ++m) {
    int r = wrow + m * 16 + (l & 15);
    offA[m] = r * 64 + (((l >> 4) ^ ((r >> 1) & 3)) * 16);
  }
#pragma unroll
  for (int n = 0; n < N_REP; ++n) {
    int r = wcol + n * 16 + (l & 15);
    offB[n] = ABYTES + r * 64 + (((l >> 4) ^ ((r >> 1) & 3)) * 16);
  }

  f32x4 acc[M_REP][N_REP] = {};
  const int KT = K / 32;

#pragma unroll
  for (int j = 0; j < 3; ++j) {
    char* bb = lds + j * BUFB;
#pragma unroll
    for (int s = 0; s < 4; ++s) async16(bb + ldst[s], gsrc[s] + j * 32);
  }

  for (int t3 = 0; t3 < KT; ++t3) {
    asm volatile("s_waitcnt lgkmcnt(0)" ::: "memory");
    __builtin_amdgcn_s_barrier();
    asm volatile("" ::: "memory");
    if (t3 + 3 < KT) {
      char* bb = lds + ((t3 + 3) & 3) * BUFB;
#pragma unroll
      for (int s = 0; s < 4; ++s) async16(bb + ldst[s], gsrc[s] + (size_t)(t3 + 3) * 32);
      asm volatile("s_waitcnt vmcnt(12)" ::: "memory");
    } else if (t3 + 3 == KT) {
      asm volatile("s_waitcnt vmcnt(8)" ::: "memory");
    } else if (t3 + 2 == KT) {
      asm volatile("s_waitcnt vmcnt(4)" ::: "memory");
    } else {
      asm volatile("s_waitcnt vmcnt(0)" ::: "memory");
    }
    __builtin_amdgcn_s_barrier();
    asm volatile("" ::: "memory");

    const char* bb = lds + (t3 & 3) * BUFB;
    short8 af[M_REP], bf[N_REP];
#pragma unroll
    for (int m = 0; m < M_REP; ++m) af[m] = *(const short8*)(bb + offA[m]);
#pragma unroll
    for (int n = 0; n < N_REP; ++n) bf[n] = *(const short8*)(bb + offB[n]);
#pragma unroll
    for (int m = 0; m < M_REP; ++m)
#pragma unroll
      for (int n = 0; n < N_REP; ++n)
        acc[m][n] = mfma16(af[m], bf[n], acc[m][n]);
  }

  const int rr = (l >> 4) * 4;
#pragma unroll
  for (int m = 0; m < M_REP; ++m) {
#pragma unroll
    for (int n = 0; n < N_REP; ++n) {
#pragma unroll
      for (int j = 0; j < 4; ++j) {
        int r = row0 + wrow + m * 16 + rr + j;
        int c = col0 + wcol + n * 16 + (l & 15);
        float v = acc[m][n][j];
        if (BIAS) v += bias[c];
        v *= scale;
        if (DIVROW) v /= rowsum[r];
        if (RES) v += resid[(size_t)r * N + c];
        if (F32OUT) O32[(size_t)r * N + c] = v;
        else if (TRANS) O16[(size_t)c * M + r] = f2bf(v);
        else O16[(size_t)r * N + c] = f2bf(v);
      }
    }
  }
}

extern "C" void kernel_launch(void* const* d_in, const int* in_sizes, int n_in,
                              void* d_out, int out_size, void* d_ws, size_t ws_size,
                              hipStream_t stream) {
  const float* x  = (const float*)d_in[0];
  const float* Wq = (const float*)d_in[1];
  const float* bq = (const float*)d_in[2];
  const float* Wk = (const float*)d_in[3];
  const float* bk = (const float*)d_in[4];
  const float* Wv = (const float*)d_in[5];
  const float* bv = (const float*)d_in[6];
  const float* Wo = (const float*)d_in[7];
  const float* bo = (const float*)d_in[8];
  float* out = (float*)d_out;

  char* p = (char*)d_ws;
  unsigned short* xb  = (unsigned short*)p; p += (size_t)NTOK * DMOD * 2;
  unsigned short* Wqb = (unsigned short*)p; p += (size_t)DMOD * DMOD * 2;
  unsigned short* Wkb = (unsigned short*)p; p += (size_t)DMOD * DMOD * 2;
  unsigned short* Wvb = (unsigned short*)p; p += (size_t)DMOD * DMOD * 2;
  unsigned short* Wob = (unsigned short*)p; p += (size_t)DMOD * DMOD * 2;
  unsigned short* Qb  = (unsigned short*)p; p += (size_t)NTOK * DMOD * 2;
  unsigned short* Kb  = (unsigned short*)p; p += (size_t)NTOK * DMOD * 2;
  unsigned short* Vt  = (unsigned short*)p; p += (size_t)DMOD * NTOK * 2;
  unsigned short* Ob  = (unsigned short*)p; p += (size_t)NTOK * DMOD * 2;
  float* rowsum       = (float*)p;          p += (size_t)NTOK * 4;
  unsigned short* S   = (unsigned short*)p; p += (size_t)NTOK * NTOK * 2;

  cast_f32_bf16<<<dim3(2048), dim3(256), 0, stream>>>(x, xb, NTOK * DMOD / 4);
  cast_f32_bf16<<<dim3(1024), dim3(256), 0, stream>>>(Wq, Wqb, DMOD * DMOD / 4);
  cast_f32_bf16<<<dim3(1024), dim3(256), 0, stream>>>(Wk, Wkb, DMOD * DMOD / 4);
  cast_f32_bf16<<<dim3(1024), dim3(256), 0, stream>>>(Wv, Wvb, DMOD * DMOD / 4);
  cast_f32_bf16<<<dim3(1024), dim3(256), 0, stream>>>(Wo, Wob, DMOD * DMOD / 4);
  zerof<<<dim3(NTOK / 256), dim3(256), 0, stream>>>(rowsum, NTOK);

  dim3 b512(512), b256(256);
  dim3 gS(NTOK / 256, NTOK / 256);      // (32,32)
  dim3 gProj(DMOD / 128, NTOK / 128);   // (8,64)

  // Q = (x Wq^T + bq)/sqrt(128);  K = x Wk^T + bk;  V^T
  gemm_pipe<128,128,2,2,true,false,false,false,false><<<gProj, b256, 0, stream>>>(xb, Wqb, Qb, nullptr, bq, nullptr, nullptr, NTOK, DMOD, DMOD, INV_SCALE);
  gemm_pipe<128,128,2,2,true,false,false,false,false><<<gProj, b256, 0, stream>>>(xb, Wkb, Kb, nullptr, bk, nullptr, nullptr, NTOK, DMOD, DMOD, 1.0f);
  gemm_pipe<128,128,2,2,true,true,false,false,false><<<gProj, b256, 0, stream>>>(xb, Wvb, Vt, nullptr, bv, nullptr, nullptr, NTOK, DMOD, DMOD, 1.0f);
  // P' = exp(Q K^T - 3), rowsum accumulated
  gemm_s_exp<<<gS, b512, 0, stream>>>(Qb, Kb, S, rowsum, NTOK, NTOK, DMOD);
  // O = (P' V) / rowsum   [N,D]
  gemm_pipe<128,128,2,2,false,false,false,false,true><<<gProj, b256, 0, stream>>>(S, Vt, Ob, nullptr, nullptr, nullptr, rowsum, NTOK, DMOD, NTOK, 1.0f);
  // out = O Wo^T + bo + x  fp32
  gemm_pipe<128,128,2,2,true,false,true,true,false><<<gProj, b256, 0, stream>>>(Ob, Wob, nullptr, out, bo, x, nullptr, NTOK, DMOD, DMOD, 1.0f);
}

// Round 11
// 562.370 us; speedup vs baseline: 1.0261x; 1.0261x over previous
//
#include <hip/hip_runtime.h>
#include <stdint.h>

// out = (softmax((x Wq^T + bq)(x Wk^T + bk)^T / sqrt(128)) (x Wv^T + bv)) Wo^T + bo + x
// N=8192, D=1024, bf16 MFMA. All GEMMs: round-6-verified 2-phase 4-buffer pipeline
// (counted vmcnt, XOR-swizzled LDS, XCD swizzle). Softmax eliminated: S-GEMM epilogue
// writes P' = exp(s-3) + accumulates f32 rowsums (round-10-verified); PV divides by rowsum.

#define NTOK 8192
#define DMOD 1024
static constexpr float INV_SCALE = 0.08838834764831845f; // 1/sqrt(128)

typedef __attribute__((ext_vector_type(8))) short short8;
typedef __attribute__((ext_vector_type(4))) float f32x4;
typedef __attribute__((ext_vector_type(4))) unsigned short u16x4;

__device__ __forceinline__ unsigned short f2bf(float f) {
  union { float f; uint32_t u; } x{f};
  uint32_t r = x.u + 0x7fffu + ((x.u >> 16) & 1u);
  return (unsigned short)(r >> 16);
}
__device__ __forceinline__ void async16(void* lds, const void* g) {
  __builtin_amdgcn_global_load_lds((const __attribute__((address_space(1))) void*)g,
                                   (__attribute__((address_space(3))) void*)lds, 16, 0, 0);
}
__device__ __forceinline__ f32x4 mfma16(short8 a, short8 b, f32x4 c) {
  return __builtin_amdgcn_mfma_f32_16x16x32_bf16(a, b, c, 0, 0, 0);
}

// ---------------- cast f32 -> bf16 ----------------
__global__ __launch_bounds__(256) void cast_f32_bf16(const float* __restrict__ in,
                                                     unsigned short* __restrict__ out, int n4) {
  int i = blockIdx.x * 256 + threadIdx.x;
  int stride = gridDim.x * 256;
  for (; i < n4; i += stride) {
    float4 v = ((const float4*)in)[i];
    u16x4 o;
    o[0] = f2bf(v.x); o[1] = f2bf(v.y); o[2] = f2bf(v.z); o[3] = f2bf(v.w);
    ((u16x4*)out)[i] = o;
  }
}

__global__ __launch_bounds__(256) void zerof(float* __restrict__ p, int n) {
  int i = blockIdx.x * 256 + threadIdx.x;
  if (i < n) p[i] = 0.f;
}

// ======== 2-phase pipelined GEMM (round-6 verified K-loop): C = A (MxK) * B^T (B NxK) ========
// BK=32, 4 LDS buffers, stage tile t+3 while computing tile t, vmcnt(12) counted wait.
// LDS XOR swizzle: linear dest + pre-swizzled source col + swizzled read (rule #21).
// Epilogues: standard (BIAS/scale/DIVROW/RES/F32OUT/TRANS) or EXPROW (P'=exp(s-3) + rowsum atomics).
template<int BM, int BN, int WM, int WN, bool BIAS, bool TRANS, bool F32OUT, bool RES, bool DIVROW, bool EXPROW>
__global__ __launch_bounds__(WM*WN*64, 2) void gemm_pipe(
    const unsigned short* __restrict__ A, const unsigned short* __restrict__ B,
    unsigned short* __restrict__ O16, float* __restrict__ O32,
    const float* __restrict__ bias, const float* __restrict__ resid,
    float* __restrict__ rowsum,
    int M, int N, int K, float scale)
{
  constexpr int THREADS = WM * WN * 64;
  constexpr int M_REP = BM / (WM * 16);
  constexpr int N_REP = BN / (WN * 16);
  constexpr int ABYTES = BM * 64;
  constexpr int BBYTES = BN * 64;
  constexpr int BUFB = ABYTES + BBYTES;
  constexpr int RPR = THREADS / 4;
  static_assert(BM == BN, "square tiles only");
  static_assert(BM * 64 == RPR * 64 * 2, "2 staging rounds per operand");

  __shared__ alignas(16) char lds[4 * BUFB];

  const int t = threadIdx.x;
  const int l = t & 63, w = t >> 6;
  const int wrow = (w / WN) * (M_REP * 16);
  const int wcol = (w % WN) * (N_REP * 16);

  // bijective XCD swizzle (m204)
  const int nwg = gridDim.x * gridDim.y;
  const int flat = blockIdx.y * gridDim.x + blockIdx.x;
  const int q8 = nwg >> 3, r8 = nwg & 7;
  const int xcd = flat & 7, pos = flat >> 3;
  const int swz = (xcd < r8 ? xcd * (q8 + 1) : r8 * (q8 + 1) + (xcd - r8) * q8) + pos;
  const int row0 = (swz / gridDim.x) * BM;
  const int col0 = (swz % gridDim.x) * BN;

  const int sr0 = t >> 2, sr1 = (t >> 2) + RPR;
  const int c0 = ((t & 3) ^ ((sr0 >> 1) & 3)) * 8;
  const int c1 = ((t & 3) ^ ((sr1 >> 1) & 3)) * 8;
  const unsigned short* gsrc[4];
  int ldst[4];
  gsrc[0] = A + (size_t)(row0 + sr0) * K + c0;  ldst[0] = t * 16;
  gsrc[1] = A + (size_t)(row0 + sr1) * K + c1;  ldst[1] = t * 16 + RPR * 64;
  gsrc[2] = B + (size_t)(col0 + sr0) * K + c0;  ldst[2] = ABYTES + t * 16;
  gsrc[3] = B + (size_t)(col0 + sr1) * K + c1;  ldst[3] = ABYTES + t * 16 + RPR * 64;

  int offA[M_REP], offB[N_REP];
#pragma unroll
  for (int m = 0; m < M_REP; ++m) {
    int r = wrow + m * 16 + (l & 15);
    offA[m] = r * 64 + (((l >> 4) ^ ((r >> 1) & 3)) * 16);
  }
#pragma unroll
  for (int n = 0; n < N_REP; ++n) {
    int r = wcol + n * 16 + (l & 15);
    offB[n] = ABYTES + r * 64 + (((l >> 4) ^ ((r >> 1) & 3)) * 16);
  }

  f32x4 acc[M_REP][N_REP] = {};
  const int KT = K / 32;

#pragma unroll
  for (int j = 0; j < 3; ++j) {
    char* bb = lds + j * BUFB;
#pragma unroll
    for (int s = 0; s < 4; ++s) async16(bb + ldst[s], gsrc[s] + j * 32);
  }

  for (int t3 = 0; t3 < KT; ++t3) {
    asm volatile("s_waitcnt lgkmcnt(0)" ::: "memory");
    __builtin_amdgcn_s_barrier();
    asm volatile("" ::: "memory");
    if (t3 + 3 < KT) {
      char* bb = lds + ((t3 + 3) & 3) * BUFB;
#pragma unroll
      for (int s = 0; s < 4; ++s) async16(bb + ldst[s], gsrc[s] + (size_t)(t3 + 3) * 32);
      asm volatile("s_waitcnt vmcnt(12)" ::: "memory");
    } else if (t3 + 3 == KT) {
      asm volatile("s_waitcnt vmcnt(8)" ::: "memory");
    } else if (t3 + 2 == KT) {
      asm volatile("s_waitcnt vmcnt(4)" ::: "memory");
    } else {
      asm volatile("s_waitcnt vmcnt(0)" ::: "memory");
    }
    __builtin_amdgcn_s_barrier();
    asm volatile("" ::: "memory");

    const char* bb = lds + (t3 & 3) * BUFB;
    short8 af[M_REP], bf[N_REP];
#pragma unroll
    for (int m = 0; m < M_REP; ++m) af[m] = *(const short8*)(bb + offA[m]);
#pragma unroll
    for (int n = 0; n < N_REP; ++n) bf[n] = *(const short8*)(bb + offB[n]);
#pragma unroll
    for (int m = 0; m < M_REP; ++m)
#pragma unroll
      for (int n = 0; n < N_REP; ++n)
        acc[m][n] = mfma16(af[m], bf[n], acc[m][n]);
  }

  // epilogue. C/D layout: col = lane&15, row = (lane>>4)*4 + j
  const int rr = (l >> 4) * 4;
  if constexpr (EXPROW) {
#pragma unroll
    for (int m = 0; m < M_REP; ++m) {
#pragma unroll
      for (int j = 0; j < 4; ++j) {
        const int r = row0 + wrow + m * 16 + rr + j;
        float ev[N_REP];
        float part = 0.f;
#pragma unroll
        for (int n = 0; n < N_REP; ++n) { ev[n] = __expf(acc[m][n][j] - 3.0f); part += ev[n]; }
#pragma unroll
        for (int o = 8; o; o >>= 1) part += __shfl_xor(part, o);
        if ((l & 15) == 0) atomicAdd(&rowsum[r], part);
#pragma unroll
        for (int n = 0; n < N_REP; ++n) {
          const int c = col0 + wcol + n * 16 + (l & 15);
          O16[(size_t)r * N + c] = f2bf(ev[n]);
        }
      }
    }
  } else {
#pragma unroll
    for (int m = 0; m < M_REP; ++m) {
#pragma unroll
      for (int n = 0; n < N_REP; ++n) {
#pragma unroll
        for (int j = 0; j < 4; ++j) {
          int r = row0 + wrow + m * 16 + rr + j;
          int c = col0 + wcol + n * 16 + (l & 15);
          float v = acc[m][n][j];
          if (BIAS) v += bias[c];
          v *= scale;
          if (DIVROW) v /= rowsum[r];
          if (RES) v += resid[(size_t)r * N + c];
          if (F32OUT) O32[(size_t)r * N + c] = v;
          else if (TRANS) O16[(size_t)c * M + r] = f2bf(v);
          else O16[(size_t)r * N + c] = f2bf(v);
        }
      }
    }
  }
}

extern "C" void kernel_launch(void* const* d_in, const int* in_sizes, int n_in,
                              void* d_out, int out_size, void* d_ws, size_t ws_size,
                              hipStream_t stream) {
  const float* x  = (const float*)d_in[0];
  const float* Wq = (const float*)d_in[1];
  const float* bq = (const float*)d_in[2];
  const float* Wk = (const float*)d_in[3];
  const float* bk = (const float*)d_in[4];
  const float* Wv = (const float*)d_in[5];
  const float* bv = (const float*)d_in[6];
  const float* Wo = (const float*)d_in[7];
  const float* bo = (const float*)d_in[8];
  float* out = (float*)d_out;

  char* p = (char*)d_ws;
  unsigned short* xb  = (unsigned short*)p; p += (size_t)NTOK * DMOD * 2;
  unsigned short* Wqb = (unsigned short*)p; p += (size_t)DMOD * DMOD * 2;
  unsigned short* Wkb = (unsigned short*)p; p += (size_t)DMOD * DMOD * 2;
  unsigned short* Wvb = (unsigned short*)p; p += (size_t)DMOD * DMOD * 2;
  unsigned short* Wob = (unsigned short*)p; p += (size_t)DMOD * DMOD * 2;
  unsigned short* Qb  = (unsigned short*)p; p += (size_t)NTOK * DMOD * 2;
  unsigned short* Kb  = (unsigned short*)p; p += (size_t)NTOK * DMOD * 2;
  unsigned short* Vt  = (unsigned short*)p; p += (size_t)DMOD * NTOK * 2;
  unsigned short* Ob  = (unsigned short*)p; p += (size_t)NTOK * DMOD * 2;
  float* rowsum       = (float*)p;          p += (size_t)NTOK * 4;
  unsigned short* S   = (unsigned short*)p; p += (size_t)NTOK * NTOK * 2;

  cast_f32_bf16<<<dim3(2048), dim3(256), 0, stream>>>(x, xb, NTOK * DMOD / 4);
  cast_f32_bf16<<<dim3(1024), dim3(256), 0, stream>>>(Wq, Wqb, DMOD * DMOD / 4);
  cast_f32_bf16<<<dim3(1024), dim3(256), 0, stream>>>(Wk, Wkb, DMOD * DMOD / 4);
  cast_f32_bf16<<<dim3(1024), dim3(256), 0, stream>>>(Wv, Wvb, DMOD * DMOD / 4);
  cast_f32_bf16<<<dim3(1024), dim3(256), 0, stream>>>(Wo, Wob, DMOD * DMOD / 4);
  zerof<<<dim3(NTOK / 256), dim3(256), 0, stream>>>(rowsum, NTOK);

  dim3 b512(512), b256(256);
  dim3 gS(NTOK / 256, NTOK / 256);      // (32,32) 256^2 tile
  dim3 gProj(DMOD / 128, NTOK / 128);   // (8,64)  128^2 tile

  // Q = (x Wq^T + bq)/sqrt(128);  K = x Wk^T + bk;  V^T = (x Wv^T + bv)^T
  gemm_pipe<128,128,2,2,true,false,false,false,false,false><<<gProj, b256, 0, stream>>>(xb, Wqb, Qb, nullptr, bq, nullptr, nullptr, NTOK, DMOD, DMOD, INV_SCALE);
  gemm_pipe<128,128,2,2,true,false,false,false,false,false><<<gProj, b256, 0, stream>>>(xb, Wkb, Kb, nullptr, bk, nullptr, nullptr, NTOK, DMOD, DMOD, 1.0f);
  gemm_pipe<128,128,2,2,true,true,false,false,false,false><<<gProj, b256, 0, stream>>>(xb, Wvb, Vt, nullptr, bv, nullptr, nullptr, NTOK, DMOD, DMOD, 1.0f);
  // P' = exp(Q K^T - 3) [bf16], rowsum accumulated (2-phase 256^2 + EXPROW epilogue)
  gemm_pipe<256,256,2,4,false,false,false,false,false,true><<<gS, b512, 0, stream>>>(Qb, Kb, S, nullptr, nullptr, nullptr, rowsum, NTOK, NTOK, DMOD, 1.0f);
  // O = (P' V) / rowsum   [N,D]
  gemm_pipe<128,128,2,2,false,false,false,false,true,false><<<gProj, b256, 0, stream>>>(S, Vt, Ob, nullptr, nullptr, nullptr, rowsum, NTOK, DMOD, NTOK, 1.0f);
  // out = O Wo^T + bo + x  fp32
  gemm_pipe<128,128,2,2,true,false,true,true,false,false><<<gProj, b256, 0, stream>>>(Ob, Wob, nullptr, out, bo, x, nullptr, NTOK, DMOD, DMOD, 1.0f);
}

// Round 12
// 516.297 us; speedup vs baseline: 1.1177x; 1.0892x over previous
//
#include <hip/hip_runtime.h>
#include <stdint.h>

// out = (softmax((x Wq^T + bq)(x Wk^T + bk)^T / sqrt(128)) (x Wv^T + bv)) Wo^T + bo + x
// N=8192, D=1024, bf16 MFMA. All GEMMs: 2-phase 4-buffer pipeline (r6-verified K-loop),
// generic byte0 staging (r10-verified), XOR-swizzled LDS, XCD swizzle.
// Softmax eliminated: S epilogue writes P'=exp(s-3); PV computes rowsum via ones-MFMA
// (linear: rowsum = P' . 1) and divides in-register. No atomics, no extra kernels.

#define NTOK 8192
#define DMOD 1024
static constexpr float INV_SCALE = 0.08838834764831845f; // 1/sqrt(128)

typedef __attribute__((ext_vector_type(8))) short short8;
typedef __attribute__((ext_vector_type(4))) float f32x4;
typedef __attribute__((ext_vector_type(4))) unsigned short u16x4;

__device__ __forceinline__ unsigned short f2bf(float f) {
  union { float f; uint32_t u; } x{f};
  uint32_t r = x.u + 0x7fffu + ((x.u >> 16) & 1u);
  return (unsigned short)(r >> 16);
}
__device__ __forceinline__ void async16(void* lds, const void* g) {
  __builtin_amdgcn_global_load_lds((const __attribute__((address_space(1))) void*)g,
                                   (__attribute__((address_space(3))) void*)lds, 16, 0, 0);
}
__device__ __forceinline__ f32x4 mfma16(short8 a, short8 b, f32x4 c) {
  return __builtin_amdgcn_mfma_f32_16x16x32_bf16(a, b, c, 0, 0, 0);
}
template<int N> __device__ __forceinline__ void waitvm() {
  if constexpr (N == 0)       asm volatile("s_waitcnt vmcnt(0)" ::: "memory");
  else if constexpr (N == 3)  asm volatile("s_waitcnt vmcnt(3)" ::: "memory");
  else if constexpr (N == 4)  asm volatile("s_waitcnt vmcnt(4)" ::: "memory");
  else if constexpr (N == 6)  asm volatile("s_waitcnt vmcnt(6)" ::: "memory");
  else if constexpr (N == 8)  asm volatile("s_waitcnt vmcnt(8)" ::: "memory");
  else if constexpr (N == 9)  asm volatile("s_waitcnt vmcnt(9)" ::: "memory");
  else if constexpr (N == 12) asm volatile("s_waitcnt vmcnt(12)" ::: "memory");
  else static_assert(N == 0, "unsupported vmcnt");
}

// ---------------- cast f32 -> bf16 ----------------
__global__ __launch_bounds__(256) void cast_f32_bf16(const float* __restrict__ in,
                                                     unsigned short* __restrict__ out, int n4) {
  int i = blockIdx.x * 256 + threadIdx.x;
  int stride = gridDim.x * 256;
  for (; i < n4; i += stride) {
    float4 v = ((const float4*)in)[i];
    u16x4 o;
    o[0] = f2bf(v.x); o[1] = f2bf(v.y); o[2] = f2bf(v.z); o[3] = f2bf(v.w);
    ((u16x4*)out)[i] = o;
  }
}

// ======== 2-phase pipelined GEMM: C = A (MxK) * B^T (B NxK), BK=32, 4 LDS buffers ========
// Stage tile t+3 while computing tile t; counted vmcnt(3*LOADS); XOR-swizzled LDS
// (linear dest + pre-swizzled source col + swizzled read). Epilogues:
//   EXPO: P' = exp(s-3) bf16      ONES: rowsum via ones-MFMA, divide in-register
//   else: BIAS/scale/RES/F32OUT/TRANS
template<int BM, int BN, int WM, int WN, bool BIAS, bool TRANS, bool F32OUT, bool RES, bool EXPO, bool ONES>
__global__ __launch_bounds__(WM*WN*64, 2) void gemm_pipe(
    const unsigned short* __restrict__ A, const unsigned short* __restrict__ B,
    unsigned short* __restrict__ O16, float* __restrict__ O32,
    const float* __restrict__ bias, const float* __restrict__ resid,
    int M, int N, int K, float scale)
{
  constexpr int THREADS = WM * WN * 64;
  constexpr int M_REP = BM / (WM * 16);
  constexpr int N_REP = BN / (WN * 16);
  constexpr int ABYTES = BM * 64;
  constexpr int BBYTES = BN * 64;
  constexpr int BUFB = ABYTES + BBYTES;
  constexpr int LOADS = BUFB / (THREADS * 16);
  static_assert(BUFB % (THREADS * 16) == 0, "staging must tile the buffer");
  static_assert(ABYTES % (THREADS * 16) == 0, "A region aligns to load boundary");

  __shared__ alignas(16) char lds[4 * BUFB];

  const int t = threadIdx.x;
  const int l = t & 63, w = t >> 6;
  const int wrow = (w / WN) * (M_REP * 16);
  const int wcol = (w % WN) * (N_REP * 16);

  // bijective XCD swizzle (m204)
  const int nwg = gridDim.x * gridDim.y;
  const int flat = blockIdx.y * gridDim.x + blockIdx.x;
  const int q8 = nwg >> 3, r8 = nwg & 7;
  const int xcd = flat & 7, pos = flat >> 3;
  const int swz = (xcd < r8 ? xcd * (q8 + 1) : r8 * (q8 + 1) + (xcd - r8) * q8) + pos;
  const int row0 = (swz / gridDim.x) * BM;
  const int col0 = (swz % gridDim.x) * BN;

  // generic staging: load li covers LDS bytes [li*THREADS*16 + t*16, +16)
  const unsigned short* gsrc[LOADS];
  int ldst[LOADS];
#pragma unroll
  for (int li = 0; li < LOADS; ++li) {
    const int byte0 = li * THREADS * 16 + t * 16;
    int r; const unsigned short* base;
    if (byte0 < ABYTES) { r = byte0 >> 6; base = A + (size_t)(row0 + r) * K; }
    else { r = (byte0 - ABYTES) >> 6; base = B + (size_t)(col0 + r) * K; }
    const int slot = (byte0 >> 4) & 3;
    gsrc[li] = base + (slot ^ ((r >> 1) & 3)) * 8;
    ldst[li] = byte0;
  }

  int offA[M_REP], offB[N_REP];
#pragma unroll
  for (int m = 0; m < M_REP; ++m) {
    int r = wrow + m * 16 + (l & 15);
    offA[m] = r * 64 + (((l >> 4) ^ ((r >> 1) & 3)) * 16);
  }
#pragma unroll
  for (int n = 0; n < N_REP; ++n) {
    int r = wcol + n * 16 + (l & 15);
    offB[n] = ABYTES + r * 64 + (((l >> 4) ^ ((r >> 1) & 3)) * 16);
  }

  short8 bones;
#pragma unroll
  for (int i = 0; i < 8; ++i) bones[i] = (short)0x3F80;   // bf16 1.0

  f32x4 acc[M_REP][N_REP] = {};
  f32x4 accrs[M_REP] = {};
  const int KT = K / 32;

#pragma unroll
  for (int j = 0; j < 3; ++j) {
    char* bb = lds + j * BUFB;
#pragma unroll
    for (int s = 0; s < LOADS; ++s) async16(bb + ldst[s], gsrc[s] + j * 32);
  }

  for (int t3 = 0; t3 < KT; ++t3) {
    asm volatile("s_waitcnt lgkmcnt(0)" ::: "memory");
    __builtin_amdgcn_s_barrier();
    asm volatile("" ::: "memory");
    if (t3 + 3 < KT) {
      char* bb = lds + ((t3 + 3) & 3) * BUFB;
#pragma unroll
      for (int s = 0; s < LOADS; ++s) async16(bb + ldst[s], gsrc[s] + (size_t)(t3 + 3) * 32);
      waitvm<3 * LOADS>();
    } else if (t3 + 3 == KT) {
      waitvm<2 * LOADS>();
    } else if (t3 + 2 == KT) {
      waitvm<LOADS>();
    } else {
      waitvm<0>();
    }
    __builtin_amdgcn_s_barrier();
    asm volatile("" ::: "memory");

    const char* bb = lds + (t3 & 3) * BUFB;
    short8 af[M_REP], bf[N_REP];
#pragma unroll
    for (int m = 0; m < M_REP; ++m) af[m] = *(const short8*)(bb + offA[m]);
#pragma unroll
    for (int n = 0; n < N_REP; ++n) bf[n] = *(const short8*)(bb + offB[n]);
#pragma unroll
    for (int m = 0; m < M_REP; ++m)
#pragma unroll
      for (int n = 0; n < N_REP; ++n)
        acc[m][n] = mfma16(af[m], bf[n], acc[m][n]);
    if constexpr (ONES) {
#pragma unroll
      for (int m = 0; m < M_REP; ++m) accrs[m] = mfma16(af[m], bones, accrs[m]);
    }
  }

  // epilogue. C/D layout: col = lane&15, row = (lane>>4)*4 + j
  const int rr = (l >> 4) * 4;
  if constexpr (EXPO) {
#pragma unroll
    for (int m = 0; m < M_REP; ++m)
#pragma unroll
      for (int n = 0; n < N_REP; ++n)
#pragma unroll
        for (int j = 0; j < 4; ++j) {
          const int r = row0 + wrow + m * 16 + rr + j;
          const int c = col0 + wcol + n * 16 + (l & 15);
          O16[(size_t)r * N + c] = f2bf(__expf(acc[m][n][j] - 3.0f));
        }
  } else if constexpr (ONES) {
#pragma unroll
    for (int m = 0; m < M_REP; ++m)
#pragma unroll
      for (int j = 0; j < 4; ++j) {
        const float inv = 1.0f / accrs[m][j];
        const int r = row0 + wrow + m * 16 + rr + j;
#pragma unroll
        for (int n = 0; n < N_REP; ++n) {
          const int c = col0 + wcol + n * 16 + (l & 15);
          O16[(size_t)r * N + c] = f2bf(acc[m][n][j] * inv);
        }
      }
  } else {
#pragma unroll
    for (int m = 0; m < M_REP; ++m)
#pragma unroll
      for (int n = 0; n < N_REP; ++n)
#pragma unroll
        for (int j = 0; j < 4; ++j) {
          int r = row0 + wrow + m * 16 + rr + j;
          int c = col0 + wcol + n * 16 + (l & 15);
          float v = acc[m][n][j];
          if (BIAS) v += bias[c];
          v *= scale;
          if (RES) v += resid[(size_t)r * N + c];
          if (F32OUT) O32[(size_t)r * N + c] = v;
          else if (TRANS) O16[(size_t)c * M + r] = f2bf(v);
          else O16[(size_t)r * N + c] = f2bf(v);
        }
  }
}

extern "C" void kernel_launch(void* const* d_in, const int* in_sizes, int n_in,
                              void* d_out, int out_size, void* d_ws, size_t ws_size,
                              hipStream_t stream) {
  const float* x  = (const float*)d_in[0];
  const float* Wq = (const float*)d_in[1];
  const float* bq = (const float*)d_in[2];
  const float* Wk = (const float*)d_in[3];
  const float* bk = (const float*)d_in[4];
  const float* Wv = (const float*)d_in[5];
  const float* bv = (const float*)d_in[6];
  const float* Wo = (const float*)d_in[7];
  const float* bo = (const float*)d_in[8];
  float* out = (float*)d_out;

  char* p = (char*)d_ws;
  unsigned short* xb  = (unsigned short*)p; p += (size_t)NTOK * DMOD * 2;
  unsigned short* Wqb = (unsigned short*)p; p += (size_t)DMOD * DMOD * 2;
  unsigned short* Wkb = (unsigned short*)p; p += (size_t)DMOD * DMOD * 2;
  unsigned short* Wvb = (unsigned short*)p; p += (size_t)DMOD * DMOD * 2;
  unsigned short* Wob = (unsigned short*)p; p += (size_t)DMOD * DMOD * 2;
  unsigned short* Qb  = (unsigned short*)p; p += (size_t)NTOK * DMOD * 2;
  unsigned short* Kb  = (unsigned short*)p; p += (size_t)NTOK * DMOD * 2;
  unsigned short* Vt  = (unsigned short*)p; p += (size_t)DMOD * NTOK * 2;
  unsigned short* Ob  = (unsigned short*)p; p += (size_t)NTOK * DMOD * 2;
  unsigned short* S   = (unsigned short*)p; p += (size_t)NTOK * NTOK * 2;

  cast_f32_bf16<<<dim3(2048), dim3(256), 0, stream>>>(x, xb, NTOK * DMOD / 4);
  cast_f32_bf16<<<dim3(1024), dim3(256), 0, stream>>>(Wq, Wqb, DMOD * DMOD / 4);
  cast_f32_bf16<<<dim3(1024), dim3(256), 0, stream>>>(Wk, Wkb, DMOD * DMOD / 4);
  cast_f32_bf16<<<dim3(1024), dim3(256), 0, stream>>>(Wv, Wvb, DMOD * DMOD / 4);
  cast_f32_bf16<<<dim3(1024), dim3(256), 0, stream>>>(Wo, Wob, DMOD * DMOD / 4);

  dim3 b512(512), b256(256);
  dim3 gS(NTOK / 256, NTOK / 256);      // (32,32)  256^2
  dim3 gProj(DMOD / 128, NTOK / 128);   // (8,64)   128^2
  dim3 gPV(DMOD / 256, NTOK / 128);     // (4,64)   128x256

  // Q = (x Wq^T + bq)/sqrt(128);  K = x Wk^T + bk;  V^T = (x Wv^T + bv)^T
  gemm_pipe<128,128,2,2,true,false,false,false,false,false><<<gProj, b256, 0, stream>>>(xb, Wqb, Qb, nullptr, bq, nullptr, NTOK, DMOD, DMOD, INV_SCALE);
  gemm_pipe<128,128,2,2,true,false,false,false,false,false><<<gProj, b256, 0, stream>>>(xb, Wkb, Kb, nullptr, bk, nullptr, NTOK, DMOD, DMOD, 1.0f);
  gemm_pipe<128,128,2,2,true,true,false,false,false,false><<<gProj, b256, 0, stream>>>(xb, Wvb, Vt, nullptr, bv, nullptr, NTOK, DMOD, DMOD, 1.0f);
  // P' = exp(Q K^T - 3)  [bf16], 256^2 tile, plain exp epilogue
  gemm_pipe<256,256,2,4,false,false,false,false,true,false><<<gS, b512, 0, stream>>>(Qb, Kb, S, nullptr, nullptr, nullptr, NTOK, NTOK, DMOD, 1.0f);
  // O = (P' V) / (P' . 1)   [N,D], 128x256 tile, rowsum via ones-MFMA
  gemm_pipe<128,256,2,4,false,false,false,false,false,true><<<gPV, b512, 0, stream>>>(S, Vt, Ob, nullptr, nullptr, nullptr, NTOK, DMOD, NTOK, 1.0f);
  // out = O Wo^T + bo + x  fp32
  gemm_pipe<128,128,2,2,true,false,true,true,false,false><<<gProj, b256, 0, stream>>>(Ob, Wob, nullptr, out, bo, x, NTOK, DMOD, DMOD, 1.0f);
}

// Round 13
// 512.590 us; speedup vs baseline: 1.1258x; 1.0072x over previous
//
#include <hip/hip_runtime.h>
#include <stdint.h>

// out = (softmax((x Wq^T + bq)(x Wk^T + bk)^T / sqrt(128)) (x Wv^T + bv)) Wo^T + bo + x
// N=8192, D=1024, bf16 MFMA. Big GEMMs (S, PV): faithful 8-phase/BK=64 schedule —
// quadrant==LDS-half via interleaved wave mapping, single fragment reads, in-place
// 2-buffer staging, counted vmcnt once per K-tile, setprio around MFMA clusters.
// Projections/out-proj: r12-verified 2-phase pipeline. Softmax fused (exp + ones-MFMA rowsum).

#define NTOK 8192
#define DMOD 1024
static constexpr float INV_SCALE = 0.08838834764831845f; // 1/sqrt(128)

typedef __attribute__((ext_vector_type(8))) short short8;
typedef __attribute__((ext_vector_type(4))) float f32x4;
typedef __attribute__((ext_vector_type(4))) unsigned short u16x4;

__device__ __forceinline__ unsigned short f2bf(float f) {
  union { float f; uint32_t u; } x{f};
  uint32_t r = x.u + 0x7fffu + ((x.u >> 16) & 1u);
  return (unsigned short)(r >> 16);
}
__device__ __forceinline__ void async16(void* lds, const void* g) {
  __builtin_amdgcn_global_load_lds((const __attribute__((address_space(1))) void*)g,
                                   (__attribute__((address_space(3))) void*)lds, 16, 0, 0);
}
__device__ __forceinline__ f32x4 mfma16(short8 a, short8 b, f32x4 c) {
  return __builtin_amdgcn_mfma_f32_16x16x32_bf16(a, b, c, 0, 0, 0);
}
template<int N> __device__ __forceinline__ void waitvm() {
  if constexpr (N == 0)       asm volatile("s_waitcnt vmcnt(0)" ::: "memory");
  else if constexpr (N == 3)  asm volatile("s_waitcnt vmcnt(3)" ::: "memory");
  else if constexpr (N == 4)  asm volatile("s_waitcnt vmcnt(4)" ::: "memory");
  else if constexpr (N == 6)  asm volatile("s_waitcnt vmcnt(6)" ::: "memory");
  else if constexpr (N == 8)  asm volatile("s_waitcnt vmcnt(8)" ::: "memory");
  else if constexpr (N == 9)  asm volatile("s_waitcnt vmcnt(9)" ::: "memory");
  else if constexpr (N == 12) asm volatile("s_waitcnt vmcnt(12)" ::: "memory");
  else static_assert(N == 0, "unsupported vmcnt");
}

// ---------------- cast f32 -> bf16 ----------------
__global__ __launch_bounds__(256) void cast_f32_bf16(const float* __restrict__ in,
                                                     unsigned short* __restrict__ out, int n4) {
  int i = blockIdx.x * 256 + threadIdx.x;
  int stride = gridDim.x * 256;
  for (; i < n4; i += stride) {
    float4 v = ((const float4*)in)[i];
    u16x4 o;
    o[0] = f2bf(v.x); o[1] = f2bf(v.y); o[2] = f2bf(v.z); o[3] = f2bf(v.w);
    ((u16x4*)out)[i] = o;
  }
}

// ======== 8-phase BK=64 GEMM: C = A (MxK) * B^T (B NxK) ========
// 8 waves (2Mg x 4Ng), interleaved frag mapping: frag m -> rows (m*2+g)*16 (m<M2 <=> A-lo),
// frag n -> cols (n*4+h)*16 (n<N2 <=> B-lo). Per K-tile: 4 quadrant phases
//   A: read A-lo,B-lo | -            | q00        C: read A-hi | stage B-lo(T+2) | q11
//   B: read B-hi      | stage A-lo   | q01        D: -         | stage B-hi,A-hi | q10 + vmcnt(TL)
// Each frag read once; each LDS half overwritten >=1 phase-barrier after its reads.
// 2 buffers (tile T in buf[T&1]; T+2 staged in-place). 8-slot XOR swizzle (128B rows).
template<int BM, int BN, bool EXPO, bool ONES>
__global__ __launch_bounds__(512, 2) void gemm_8p(
    const unsigned short* __restrict__ A, const unsigned short* __restrict__ B,
    unsigned short* __restrict__ O16, int M, int N, int K)
{
  constexpr int M_REP = BM / 32;
  constexpr int N_REP = BN / 64;
  constexpr int M2 = M_REP / 2, N2 = N_REP / 2;
  constexpr int ABY = BM * 128;          // BM rows x 64 bf16 x 2B
  constexpr int BBY = BN * 128;
  constexpr int BUFB = ABY + BBY;
  constexpr int HLA = (ABY / 2) / 8192;  // loads per A-half (512 thr x 16B)
  constexpr int HLB = (BBY / 2) / 8192;
  constexpr int TL = 2 * (HLA + HLB);    // loads per K-tile
  static_assert((ABY / 2) % 8192 == 0 && (BBY / 2) % 8192 == 0);

  __shared__ alignas(16) char lds[2 * BUFB];

  const int t = threadIdx.x;
  const int l = t & 63, w = t >> 6;
  const int g = w >> 2, h = w & 3;

  // bijective XCD swizzle (m204)
  const int nwg = gridDim.x * gridDim.y;
  const int flat = blockIdx.y * gridDim.x + blockIdx.x;
  const int q8 = nwg >> 3, r8 = nwg & 7;
  const int xcd = flat & 7, pos = flat >> 3;
  const int swz = (xcd < r8 ? xcd * (q8 + 1) : r8 * (q8 + 1) + (xcd - r8) * q8) + pos;
  const int row0 = (swz / gridDim.x) * BM;
  const int col0 = (swz % gridDim.x) * BN;

  // staging lists (source col pre-swizzled: slot ^ (row&7); LDS dest linear)
  const unsigned short* gAlo[HLA]; int dAlo[HLA];
  const unsigned short* gAhi[HLA]; int dAhi[HLA];
  const unsigned short* gBlo[HLB]; int dBlo[HLB];
  const unsigned short* gBhi[HLB]; int dBhi[HLB];
#pragma unroll
  for (int i = 0; i < HLA; ++i) {
    const int rel = i * 8192 + t * 16;
    const int slot = (rel >> 4) & 7;
    { int row = rel >> 7;
      gAlo[i] = A + (size_t)(row0 + row) * K + ((slot ^ (row & 7)) * 8);
      dAlo[i] = rel; }
    { int row = (rel >> 7) + BM / 2;
      gAhi[i] = A + (size_t)(row0 + row) * K + ((slot ^ (row & 7)) * 8);
      dAhi[i] = ABY / 2 + rel; }
  }
#pragma unroll
  for (int i = 0; i < HLB; ++i) {
    const int rel = i * 8192 + t * 16;
    const int slot = (rel >> 4) & 7;
    { int row = rel >> 7;
      gBlo[i] = B + (size_t)(col0 + row) * K + ((slot ^ (row & 7)) * 8);
      dBlo[i] = ABY + rel; }
    { int row = (rel >> 7) + BN / 2;
      gBhi[i] = B + (size_t)(col0 + row) * K + ((slot ^ (row & 7)) * 8);
      dBhi[i] = ABY + BBY / 2 + rel; }
  }

  // fragment read offsets: row r, kslot k, logical slot k*4+(l>>4), stored ^(r&7)
  int offA[M_REP][2], offB[N_REP][2];
#pragma unroll
  for (int m = 0; m < M_REP; ++m) {
    const int r = (m * 2 + g) * 16 + (l & 15);
#pragma unroll
    for (int k = 0; k < 2; ++k)
      offA[m][k] = r * 128 + (((k * 4 + (l >> 4)) ^ (r & 7)) * 16);
  }
#pragma unroll
  for (int n = 0; n < N_REP; ++n) {
    const int r = (n * 4 + h) * 16 + (l & 15);
#pragma unroll
    for (int k = 0; k < 2; ++k)
      offB[n][k] = ABY + r * 128 + (((k * 4 + (l >> 4)) ^ (r & 7)) * 16);
  }

  short8 bones;
#pragma unroll
  for (int i = 0; i < 8; ++i) bones[i] = (short)0x3F80;   // bf16 1.0

  f32x4 acc[M_REP][N_REP] = {};
  f32x4 accrs[M_REP] = {};
  const int KT = K / 64;

  // prologue: stage tiles 0 and 1 fully
#pragma unroll
  for (int j = 0; j < 2; ++j) {
    char* bb = lds + j * BUFB;
#pragma unroll
    for (int i = 0; i < HLA; ++i) async16(bb + dAlo[i], gAlo[i] + j * 64);
#pragma unroll
    for (int i = 0; i < HLB; ++i) async16(bb + dBlo[i], gBlo[i] + j * 64);
#pragma unroll
    for (int i = 0; i < HLB; ++i) async16(bb + dBhi[i], gBhi[i] + j * 64);
#pragma unroll
    for (int i = 0; i < HLA; ++i) async16(bb + dAhi[i], gAhi[i] + j * 64);
  }
  waitvm<TL>();                      // tile 0 landed (tile 1 in flight)
  __builtin_amdgcn_s_barrier();

  for (int T = 0; T < KT; ++T) {
    const char* rb = lds + (T & 1) * BUFB;
    char* sb = lds + (T & 1) * BUFB;          // T+2 goes in-place
    const bool st = (T + 2) < KT;
    const size_t ko = (size_t)(T + 2) * 64;
    short8 fAlo[M2][2], fAhi[M2][2], fBlo[N2][2], fBhi[N2][2];

    // ---- Phase A: read A-lo + B-lo, MFMA q00 ----
#pragma unroll
    for (int m = 0; m < M2; ++m) { fAlo[m][0] = *(const short8*)(rb + offA[m][0]);
                                   fAlo[m][1] = *(const short8*)(rb + offA[m][1]); }
#pragma unroll
    for (int n = 0; n < N2; ++n) { fBlo[n][0] = *(const short8*)(rb + offB[n][0]);
                                   fBlo[n][1] = *(const short8*)(rb + offB[n][1]); }
    __builtin_amdgcn_s_barrier();
    asm volatile("s_waitcnt lgkmcnt(0)" ::: "memory");
    __builtin_amdgcn_s_setprio(1);
#pragma unroll
    for (int m = 0; m < M2; ++m)
#pragma unroll
      for (int n = 0; n < N2; ++n) {
        acc[m][n] = mfma16(fAlo[m][0], fBlo[n][0], acc[m][n]);
        acc[m][n] = mfma16(fAlo[m][1], fBlo[n][1], acc[m][n]);
      }
    if constexpr (ONES) {
#pragma unroll
      for (int m = 0; m < M2; ++m) {
        accrs[m] = mfma16(fAlo[m][0], bones, accrs[m]);
        accrs[m] = mfma16(fAlo[m][1], bones, accrs[m]);
      }
    }
    __builtin_amdgcn_s_setprio(0);
    __builtin_amdgcn_s_barrier();

    // ---- Phase B: read B-hi, stage A-lo(T+2), MFMA q01 ----
#pragma unroll
    for (int n = 0; n < N2; ++n) { fBhi[n][0] = *(const short8*)(rb + offB[N2 + n][0]);
                                   fBhi[n][1] = *(const short8*)(rb + offB[N2 + n][1]); }
    if (st) {
#pragma unroll
      for (int i = 0; i < HLA; ++i) async16(sb + dAlo[i], gAlo[i] + ko);
    }
    __builtin_amdgcn_s_barrier();
    asm volatile("s_waitcnt lgkmcnt(0)" ::: "memory");
    __builtin_amdgcn_s_setprio(1);
#pragma unroll
    for (int m = 0; m < M2; ++m)
#pragma unroll
      for (int n = 0; n < N2; ++n) {
        acc[m][N2 + n] = mfma16(fAlo[m][0], fBhi[n][0], acc[m][N2 + n]);
        acc[m][N2 + n] = mfma16(fAlo[m][1], fBhi[n][1], acc[m][N2 + n]);
      }
    __builtin_amdgcn_s_setprio(0);
    __builtin_amdgcn_s_barrier();

    // ---- Phase C: read A-hi, stage B-lo(T+2), MFMA q11 ----
#pragma unroll
    for (int m = 0; m < M2; ++m) { fAhi[m][0] = *(const short8*)(rb + offA[M2 + m][0]);
                                   fAhi[m][1] = *(const short8*)(rb + offA[M2 + m][1]); }
    if (st) {
#pragma unroll
      for (int i = 0; i < HLB; ++i) async16(sb + dBlo[i], gBlo[i] + ko);
    }
    __builtin_amdgcn_s_barrier();
    asm volatile("s_waitcnt lgkmcnt(0)" ::: "memory");
    __builtin_amdgcn_s_setprio(1);
#pragma unroll
    for (int m = 0; m < M2; ++m)
#pragma unroll
      for (int n = 0; n < N2; ++n) {
        acc[M2 + m][N2 + n] = mfma16(fAhi[m][0], fBhi[n][0], acc[M2 + m][N2 + n]);
        acc[M2 + m][N2 + n] = mfma16(fAhi[m][1], fBhi[n][1], acc[M2 + m][N2 + n]);
      }
    if constexpr (ONES) {
#pragma unroll
      for (int m = 0; m < M2; ++m) {
        accrs[M2 + m] = mfma16(fAhi[m][0], bones, accrs[M2 + m]);
        accrs[M2 + m] = mfma16(fAhi[m][1], bones, accrs[M2 + m]);
      }
    }
    __builtin_amdgcn_s_setprio(0);
    __builtin_amdgcn_s_barrier();

    // ---- Phase D: stage B-hi,A-hi(T+2), MFMA q10, counted vmcnt ----
    if (st) {
#pragma unroll
      for (int i = 0; i < HLB; ++i) async16(sb + dBhi[i], gBhi[i] + ko);
#pragma unroll
      for (int i = 0; i < HLA; ++i) async16(sb + dAhi[i], gAhi[i] + ko);
    }
    __builtin_amdgcn_s_setprio(1);
#pragma unroll
    for (int m = 0; m < M2; ++m)
#pragma unroll
      for (int n = 0; n < N2; ++n) {
        acc[M2 + m][n] = mfma16(fAhi[m][0], fBlo[n][0], acc[M2 + m][n]);
        acc[M2 + m][n] = mfma16(fAhi[m][1], fBlo[n][1], acc[M2 + m][n]);
      }
    __builtin_amdgcn_s_setprio(0);
    if (st) waitvm<TL>();                  // retire tile T+1; T+2 stays in flight
    else if (T + 1 < KT) waitvm<0>();
    __builtin_amdgcn_s_barrier();
  }

  // epilogue. C/D: col = lane&15, row = (lane>>4)*4 + j; interleaved tile mapping.
  const int rr = (l >> 4) * 4;
  if constexpr (EXPO) {
#pragma unroll
    for (int m = 0; m < M_REP; ++m)
#pragma unroll
      for (int n = 0; n < N_REP; ++n)
#pragma unroll
        for (int j = 0; j < 4; ++j) {
          const int r = row0 + (m * 2 + g) * 16 + rr + j;
          const int c = col0 + (n * 4 + h) * 16 + (l & 15);
          O16[(size_t)r * N + c] = f2bf(__expf(acc[m][n][j] - 3.0f));
        }
  } else {
#pragma unroll
    for (int m = 0; m < M_REP; ++m)
#pragma unroll
      for (int j = 0; j < 4; ++j) {
        const float inv = 1.0f / accrs[m][j];
        const int r = row0 + (m * 2 + g) * 16 + rr + j;
#pragma unroll
        for (int n = 0; n < N_REP; ++n) {
          const int c = col0 + (n * 4 + h) * 16 + (l & 15);
          O16[(size_t)r * N + c] = f2bf(acc[m][n][j] * inv);
        }
      }
  }
}

// ======== 2-phase pipelined GEMM (r12-verified) for projections / out-proj ========
template<int BM, int BN, int WM, int WN, bool BIAS, bool TRANS, bool F32OUT, bool RES>
__global__ __launch_bounds__(WM*WN*64, 2) void gemm_pipe(
    const unsigned short* __restrict__ A, const unsigned short* __restrict__ B,
    unsigned short* __restrict__ O16, float* __restrict__ O32,
    const float* __restrict__ bias, const float* __restrict__ resid,
    int M, int N, int K, float scale)
{
  constexpr int THREADS = WM * WN * 64;
  constexpr int M_REP = BM / (WM * 16);
  constexpr int N_REP = BN / (WN * 16);
  constexpr int ABYTES = BM * 64;
  constexpr int BBYTES = BN * 64;
  constexpr int BUFB = ABYTES + BBYTES;
  constexpr int LOADS = BUFB / (THREADS * 16);
  static_assert(BUFB % (THREADS * 16) == 0);
  static_assert(ABYTES % (THREADS * 16) == 0);

  __shared__ alignas(16) char lds[4 * BUFB];

  const int t = threadIdx.x;
  const int l = t & 63, w = t >> 6;
  const int wrow = (w / WN) * (M_REP * 16);
  const int wcol = (w % WN) * (N_REP * 16);

  const int nwg = gridDim.x * gridDim.y;
  const int flat = blockIdx.y * gridDim.x + blockIdx.x;
  const int q8 = nwg >> 3, r8 = nwg & 7;
  const int xcd = flat & 7, pos = flat >> 3;
  const int swz = (xcd < r8 ? xcd * (q8 + 1) : r8 * (q8 + 1) + (xcd - r8) * q8) + pos;
  const int row0 = (swz / gridDim.x) * BM;
  const int col0 = (swz % gridDim.x) * BN;

  const unsigned short* gsrc[LOADS];
  int ldst[LOADS];
#pragma unroll
  for (int li = 0; li < LOADS; ++li) {
    const int byte0 = li * THREADS * 16 + t * 16;
    int r; const unsigned short* base;
    if (byte0 < ABYTES) { r = byte0 >> 6; base = A + (size_t)(row0 + r) * K; }
    else { r = (byte0 - ABYTES) >> 6; base = B + (size_t)(col0 + r) * K; }
    const int slot = (byte0 >> 4) & 3;
    gsrc[li] = base + (slot ^ ((r >> 1) & 3)) * 8;
    ldst[li] = byte0;
  }

  int offA[M_REP], offB[N_REP];
#pragma unroll
  for (int m = 0; m < M_REP; ++m) {
    int r = wrow + m * 16 + (l & 15);
    offA[m] = r * 64 + (((l >> 4) ^ ((r >> 1) & 3)) * 16);
  }
#pragma unroll
  for (int n = 0; n < N_REP; ++n) {
    int r = wcol + n * 16 + (l & 15);
    offB[n] = ABYTES + r * 64 + (((l >> 4) ^ ((r >> 1) & 3)) * 16);
  }

  f32x4 acc[M_REP][N_REP] = {};
  const int KT = K / 32;

#pragma unroll
  for (int j = 0; j < 3; ++j) {
    char* bb = lds + j * BUFB;
#pragma unroll
    for (int s = 0; s < LOADS; ++s) async16(bb + ldst[s], gsrc[s] + j * 32);
  }

  for (int t3 = 0; t3 < KT; ++t3) {
    asm volatile("s_waitcnt lgkmcnt(0)" ::: "memory");
    __builtin_amdgcn_s_barrier();
    asm volatile("" ::: "memory");
    if (t3 + 3 < KT) {
      char* bb = lds + ((t3 + 3) & 3) * BUFB;
#pragma unroll
      for (int s = 0; s < LOADS; ++s) async16(bb + ldst[s], gsrc[s] + (size_t)(t3 + 3) * 32);
      waitvm<3 * LOADS>();
    } else if (t3 + 3 == KT) {
      waitvm<2 * LOADS>();
    } else if (t3 + 2 == KT) {
      waitvm<LOADS>();
    } else {
      waitvm<0>();
    }
    __builtin_amdgcn_s_barrier();
    asm volatile("" ::: "memory");

    const char* bb = lds + (t3 & 3) * BUFB;
    short8 af[M_REP], bf[N_REP];
#pragma unroll
    for (int m = 0; m < M_REP; ++m) af[m] = *(const short8*)(bb + offA[m]);
#pragma unroll
    for (int n = 0; n < N_REP; ++n) bf[n] = *(const short8*)(bb + offB[n]);
#pragma unroll
    for (int m = 0; m < M_REP; ++m)
#pragma unroll
      for (int n = 0; n < N_REP; ++n)
        acc[m][n] = mfma16(af[m], bf[n], acc[m][n]);
  }

  const int rr = (l >> 4) * 4;
#pragma unroll
  for (int m = 0; m < M_REP; ++m)
#pragma unroll
    for (int n = 0; n < N_REP; ++n)
#pragma unroll
      for (int j = 0; j < 4; ++j) {
        int r = row0 + wrow + m * 16 + rr + j;
        int c = col0 + wcol + n * 16 + (l & 15);
        float v = acc[m][n][j];
        if (BIAS) v += bias[c];
        v *= scale;
        if (RES) v += resid[(size_t)r * N + c];
        if (F32OUT) O32[(size_t)r * N + c] = v;
        else if (TRANS) O16[(size_t)c * M + r] = f2bf(v);
        else O16[(size_t)r * N + c] = f2bf(v);
      }
}

extern "C" void kernel_launch(void* const* d_in, const int* in_sizes, int n_in,
                              void* d_out, int out_size, void* d_ws, size_t ws_size,
                              hipStream_t stream) {
  const float* x  = (const float*)d_in[0];
  const float* Wq = (const float*)d_in[1];
  const float* bq = (const float*)d_in[2];
  const float* Wk = (const float*)d_in[3];
  const float* bk = (const float*)d_in[4];
  const float* Wv = (const float*)d_in[5];
  const float* bv = (const float*)d_in[6];
  const float* Wo = (const float*)d_in[7];
  const float* bo = (const float*)d_in[8];
  float* out = (float*)d_out;

  char* p = (char*)d_ws;
  unsigned short* xb  = (unsigned short*)p; p += (size_t)NTOK * DMOD * 2;
  unsigned short* Wqb = (unsigned short*)p; p += (size_t)DMOD * DMOD * 2;
  unsigned short* Wkb = (unsigned short*)p; p += (size_t)DMOD * DMOD * 2;
  unsigned short* Wvb = (unsigned short*)p; p += (size_t)DMOD * DMOD * 2;
  unsigned short* Wob = (unsigned short*)p; p += (size_t)DMOD * DMOD * 2;
  unsigned short* Qb  = (unsigned short*)p; p += (size_t)NTOK * DMOD * 2;
  unsigned short* Kb  = (unsigned short*)p; p += (size_t)NTOK * DMOD * 2;
  unsigned short* Vt  = (unsigned short*)p; p += (size_t)DMOD * NTOK * 2;
  unsigned short* Ob  = (unsigned short*)p; p += (size_t)NTOK * DMOD * 2;
  unsigned short* S   = (unsigned short*)p; p += (size_t)NTOK * NTOK * 2;

  cast_f32_bf16<<<dim3(2048), dim3(256), 0, stream>>>(x, xb, NTOK * DMOD / 4);
  cast_f32_bf16<<<dim3(1024), dim3(256), 0, stream>>>(Wq, Wqb, DMOD * DMOD / 4);
  cast_f32_bf16<<<dim3(1024), dim3(256), 0, stream>>>(Wk, Wkb, DMOD * DMOD / 4);
  cast_f32_bf16<<<dim3(1024), dim3(256), 0, stream>>>(Wv, Wvb, DMOD * DMOD / 4);
  cast_f32_bf16<<<dim3(1024), dim3(256), 0, stream>>>(Wo, Wob, DMOD * DMOD / 4);

  dim3 b512(512), b256(256);
  dim3 gS(NTOK / 256, NTOK / 256);      // (32,32)  256^2
  dim3 gProj(DMOD / 128, NTOK / 128);   // (8,64)   128^2
  dim3 gPV(DMOD / 256, NTOK / 128);     // (4,64)   128x256

  // Q = (x Wq^T + bq)/sqrt(128);  K = x Wk^T + bk;  V^T = (x Wv^T + bv)^T
  gemm_pipe<128,128,2,2,true,false,false,false><<<gProj, b256, 0, stream>>>(xb, Wqb, Qb, nullptr, bq, nullptr, NTOK, DMOD, DMOD, INV_SCALE);
  gemm_pipe<128,128,2,2,true,false,false,false><<<gProj, b256, 0, stream>>>(xb, Wkb, Kb, nullptr, bk, nullptr, NTOK, DMOD, DMOD, 1.0f);
  gemm_pipe<128,128,2,2,true,true,false,false><<<gProj, b256, 0, stream>>>(xb, Wvb, Vt, nullptr, bv, nullptr, NTOK, DMOD, DMOD, 1.0f);
  // P' = exp(Q K^T - 3)  [bf16], 8-phase 256^2
  gemm_8p<256,256,true,false><<<gS, b512, 0, stream>>>(Qb, Kb, S, NTOK, NTOK, DMOD);
  // O = (P' V) / (P' . 1)  [N,D], 8-phase 128x256 with ones-MFMA rowsum
  gemm_8p<128,256,false,true><<<gPV, b512, 0, stream>>>(S, Vt, Ob, NTOK, DMOD, NTOK);
  // out = O Wo^T + bo + x  fp32
  gemm_pipe<128,128,2,2,true,false,true,true><<<gProj, b256, 0, stream>>>(Ob, Wob, nullptr, out, bo, x, NTOK, DMOD, DMOD, 1.0f);
}